// Round 11
// baseline (252.670 us; speedup 1.0000x reference)
//
#include <hip/hip_runtime.h>

typedef unsigned short u16;
typedef unsigned int   u32;
typedef float  f32x4   __attribute__((ext_vector_type(4)));
typedef __bf16 bf16x8  __attribute__((ext_vector_type(8)));
typedef u16    u16x8   __attribute__((ext_vector_type(8)));
typedef u16    u16x4   __attribute__((ext_vector_type(4)));
typedef u32    u32x2   __attribute__((ext_vector_type(2)));
typedef u32    u32x4   __attribute__((ext_vector_type(4)));

#define HIDDEN 2048
#define SEQ    2048
#define NHEADS 16
#define HD     128
#define BATCH  2
#define QSTR   4096   // fused Q|K row stride

typedef const __attribute__((address_space(3))) u16* lptr;

__device__ __forceinline__ u16 f2bf(float f) {
  u32 u = __builtin_bit_cast(u32, f);
  u += 0x7FFFu + ((u >> 16) & 1u);          // RNE
  return (u16)(u >> 16);
}
__device__ __forceinline__ u32 pk2(float a, float b) {
  __bf16 x = (__bf16)a, y = (__bf16)b;
  return (u32)__builtin_bit_cast(u16, x) | ((u32)__builtin_bit_cast(u16, y) << 16);
}
__device__ __forceinline__ bf16x8 ld_frag(const u16* p) {
  return __builtin_bit_cast(bf16x8, *(const u32x4*)p);
}
__device__ __forceinline__ void gload_lds16(const u16* g, u16* l) {
  __builtin_amdgcn_global_load_lds((const __attribute__((address_space(1))) u32*)g,
                                   (__attribute__((address_space(3))) u32*)l, 16, 0, 0);
}

// inline-asm LDS read: compiler inserts no auto-waits; we count lgkmcnt manually.
#define DSR(dst, base, lit) \
  asm volatile("ds_read_b128 %0, %1 offset:" lit : "=v"(dst) : "v"(base))

#define MFMA16(d, a, b) d = __builtin_amdgcn_mfma_f32_16x16x32_bf16(a, b, d, 0, 0, 0)

// ---------------- fp32 -> bf16 convert: 6 equal segments (4 weights + 2 x-halves) ----------------
__global__ __launch_bounds__(256) void cvt6_kernel(
    const float* __restrict__ x,
    const float* __restrict__ wq, const float* __restrict__ wk,
    const float* __restrict__ wv, const float* __restrict__ wo,
    u16* __restrict__ xb, u16* __restrict__ wqb, u16* __restrict__ wkb,
    u16* __restrict__ wvb, u16* __restrict__ wob, int n4) {
  const float* src;
  u16* dst;
  switch (blockIdx.y) {
    case 0:  src = wq; dst = wqb; break;
    case 1:  src = wk; dst = wkb; break;
    case 2:  src = wv; dst = wvb; break;
    case 3:  src = wo; dst = wob; break;
    case 4:  src = x;  dst = xb;  break;
    default: src = x + (size_t)n4 * 4; dst = xb + (size_t)n4 * 4; break;
  }
  int stride = gridDim.x * blockDim.x;
  for (int i = blockIdx.x * blockDim.x + threadIdx.x; i < n4; i += stride) {
    f32x4 v = ((const f32x4*)src)[i];
    u16x4 o;
    o[0] = f2bf(v[0]); o[1] = f2bf(v[1]); o[2] = f2bf(v[2]); o[3] = f2bf(v[3]);
    *(u16x4*)(dst + (size_t)i * 4) = o;
  }
}

// ---------------- fused QKV projection: 256Mx192N tile, BK=64, 8-wave, asm-counted pipeline ----------------
// PROVEN 118us config (round-7 bench): 2-phase counted waits, stage(t+2) issued before MFMA-Y.
__global__ __launch_bounds__(512, 2) void gemm_qkv(
    const u16* __restrict__ A, const u16* __restrict__ Bt,
    const float* __restrict__ bq, const float* __restrict__ bk,
    const float* __restrict__ bv,
    u16* __restrict__ qk, u16* __restrict__ vtb, float qscale)
{
  __shared__ __attribute__((aligned(16))) u16 As[2][16384];  // 64 KiB
  __shared__ __attribute__((aligned(16))) u16 Bs[2][12288];  // 48 KiB

  const int tid  = threadIdx.x;
  const int lane = tid & 63;
  const int wave = tid >> 6;
  const int l15  = lane & 15;
  const int g    = lane >> 4;
  const int wm   = wave >> 2;            // 0..1 (M half, 128 rows)
  const int wn   = wave & 3;             // 0..3 (N quarter, 48 cols)

  // grid 512 = 8 XCD * (4 Ntiles * 16 Mtiles); bijective
  const int id  = blockIdx.x;
  const int xcd = id & 7;
  const int c   = id >> 3;               // 0..63
  const int tileN = (xcd * 4 + (c >> 4)) * 192;
  const int tileM = (c & 15) << 8;

  // staging: thread covers row (tid>>3) of each 64-row round, chunk (tid&7)
  const int srow = tid >> 3;
  const int gch8 = ((tid & 7) ^ (srow & 7)) * 8;     // pre-swizzled global chunk
  const u16* agp = A  + (size_t)(tileM + srow) * HIDDEN + gch8;
  const u16* bgp = Bt + (size_t)(tileN + srow) * HIDDEN + gch8;
  u16* asp = (u16*)&As[0][0] + tid * 8;
  u16* bsp = (u16*)&Bs[0][0] + tid * 8;

  auto stage = [&](int buf, int ko) {
    u16* ad = asp + buf * 16384;
    u16* bd = bsp + buf * 12288;
#pragma unroll
    for (int r = 0; r < 4; ++r)
      gload_lds16(agp + (size_t)r * 64 * HIDDEN + ko, ad + r * 4096);
#pragma unroll
    for (int r = 0; r < 3; ++r)
      gload_lds16(bgp + (size_t)r * 64 * HIDDEN + ko, bd + r * 4096);
  };

  // fragment read bases (asm, byte offsets in literals): row stride 16 rows = 2048 B
  const int sw = l15 & 7;
  const int c0 = (g ^ sw) * 8;           // k0 chunk (elements)
  const int c1 = ((g ^ sw) ^ 4) * 8;     // k1 chunk
  lptr aT = (lptr)&As[0][0] + (size_t)(wm * 128 + l15) * 64;
  lptr bT = (lptr)&Bs[0][0] + (size_t)(wn * 48 + l15) * 64;

  f32x4 acc[8][3] = {};
  bf16x8 Xa[8], Xb[3], Ya[8], Yb[3];

#define ISSUE_SET(Sa, Sb, ab, bb)      \
  DSR(Sa[0], ab, "0");                 \
  DSR(Sa[1], ab, "2048");              \
  DSR(Sa[2], ab, "4096");              \
  DSR(Sa[3], ab, "6144");              \
  DSR(Sa[4], ab, "8192");              \
  DSR(Sa[5], ab, "10240");             \
  DSR(Sa[6], ab, "12288");             \
  DSR(Sa[7], ab, "14336");             \
  DSR(Sb[0], bb, "0");                 \
  DSR(Sb[1], bb, "2048");              \
  DSR(Sb[2], bb, "4096");

#define MFMA24(Sa, Sb)                                                                    \
  _Pragma("unroll")                                                                       \
  for (int mf = 0; mf < 8; ++mf) {                                                        \
    _Pragma("unroll")                                                                     \
    for (int nf = 0; nf < 3; ++nf)                                                        \
      acc[mf][nf] = __builtin_amdgcn_mfma_f32_16x16x32_bf16(Sa[mf], Sb[nf], acc[mf][nf], 0, 0, 0); \
  }

  // ---- prologue: stage tiles 0,1; wait tile0; issue X=(buf0,k0)
  stage(0, 0);
  stage(1, 64);
  asm volatile("s_waitcnt vmcnt(7)" ::: "memory");
  __builtin_amdgcn_s_barrier();
  __builtin_amdgcn_sched_barrier(0);
  {
    lptr ab = aT + c0;
    lptr bb = bT + c0;
    ISSUE_SET(Xa, Xb, ab, bb)
  }

#pragma unroll 2
  for (int t = 0; t < 32; ++t) {
    const int cur = t & 1;
    lptr aC = aT + cur * 16384;
    lptr bC = bT + cur * 12288;
    // [1] Y <- (cur, k1)
    {
      lptr ab = aC + c1;
      lptr bb = bC + c1;
      ISSUE_SET(Ya, Yb, ab, bb)
    }
    // [2] X ready (Y in flight)
    asm volatile("s_waitcnt lgkmcnt(11)" ::: "memory");
    __builtin_amdgcn_sched_barrier(0);
    __builtin_amdgcn_s_setprio(1);
    MFMA24(Xa, Xb)
    __builtin_amdgcn_s_setprio(0);
    // [3] Y ready; own reads of cur all retired
    asm volatile("s_waitcnt lgkmcnt(0)" ::: "memory");
    __builtin_amdgcn_sched_barrier(0);
    // [4] ALL waves' reads of cur retired -> cur may be overwritten
    __builtin_amdgcn_s_barrier();
    __builtin_amdgcn_sched_barrier(0);
    // [5] stage t+2 -> cur; issue+flight overlap MFMA Y
    if (t < 30) stage(cur, (t + 2) * 64);
    __builtin_amdgcn_sched_barrier(0);
    __builtin_amdgcn_s_setprio(1);
    MFMA24(Ya, Yb)
    __builtin_amdgcn_s_setprio(0);
    __builtin_amdgcn_sched_barrier(0);
    // [6] own t+1 landed (t+2 stays in flight)
    if (t < 30) {
      asm volatile("s_waitcnt vmcnt(7)" ::: "memory");
    } else {
      asm volatile("s_waitcnt vmcnt(0)" ::: "memory");
    }
    __builtin_amdgcn_s_barrier();
    __builtin_amdgcn_sched_barrier(0);
    // [7] X <- (nxt, k0)
    if (t < 31) {
      lptr ab = aT + (cur ^ 1) * 16384 + c0;
      lptr bb = bT + (cur ^ 1) * 12288 + c0;
      ISSUE_SET(Xa, Xb, ab, bb)
    }
  }

  // ---------- epilogue: Q|K -> qk (scaled, biased), V -> transposed vtb
#pragma unroll
  for (int mi = 0; mi < 8; ++mi) {
#pragma unroll
    for (int ni = 0; ni < 3; ++ni) {
      const int gcb = tileN + wn * 48 + ni * 16;
      const int seg = gcb >> 11;                     // 0=Q 1=K 2=V
      const int gc  = gcb + l15;
      const float bvv = ((seg == 0) ? bq : (seg == 1) ? bk : bv)[gc & 2047];
      if (seg < 2) {
        const float scl = (seg == 0) ? qscale : 1.f;
#pragma unroll
        for (int j = 0; j < 4; ++j) {
          const int gr = tileM + wm * 128 + mi * 16 + g * 4 + j;
          qk[(size_t)gr * QSTR + gc] = f2bf((acc[mi][ni][j] + bvv) * scl);
        }
      } else {
        const int dglob = gc - 4096;
        const int hh = dglob >> 7, dd = dglob & 127;
        const int srow0 = tileM + wm * 128 + mi * 16 + g * 4;
        const int bb = srow0 >> 11, ss = srow0 & 2047;
        u16x4 o;
#pragma unroll
        for (int j = 0; j < 4; ++j) o[j] = f2bf(acc[mi][ni][j] + bvv);
        *(u16x4*)(vtb + ((size_t)((bb * NHEADS + hh) * HD + dd)) * SEQ + ss) = o;
      }
    }
  }
#undef ISSUE_SET
#undef MFMA24
}

// ---------------- output projection: 128x128 tile, BK=64, 4-wave, 2 blocks/CU (m97-class TLP) ----------------
// Same counted-wait skeleton; cross-block TLP hides the per-tile lockstep overhead.
// grid 512 = 8 XCD * (2 Ntiles * 32 Mtiles) = 2 balanced rounds at 2 blocks/CU.
__global__ __launch_bounds__(256, 2) void gemm_o(
    const u16* __restrict__ A, const u16* __restrict__ Bt,
    const float* __restrict__ bias, float* __restrict__ Cout)
{
  __shared__ __attribute__((aligned(16))) u16 As[2][8192];  // 128x64 x2 = 32 KiB
  __shared__ __attribute__((aligned(16))) u16 Bs[2][8192];  // 128x64 x2 = 32 KiB

  const int tid  = threadIdx.x;
  const int lane = tid & 63;
  const int wave = tid >> 6;             // 0..3
  const int l15  = lane & 15;
  const int g    = lane >> 4;
  const int wm   = wave >> 1;            // 0..1 (64-row half)
  const int wn   = wave & 1;             // 0..1 (64-col half)

  const int id  = blockIdx.x;
  const int xcd = id & 7;
  const int c   = id >> 3;               // 0..63
  const int tileN = (xcd * 2 + (c >> 5)) << 7;
  const int tileM = (c & 31) << 7;

  const int sr   = tid >> 3;             // 0..31
  const int sgc  = ((tid & 7) ^ (sr & 7)) * 8;       // pre-swizzled global chunk
  const u16* agp = A  + (size_t)(tileM + sr) * HIDDEN + sgc;
  const u16* bgp = Bt + (size_t)(tileN + sr) * HIDDEN + sgc;
  u16* asp = (u16*)&As[0][0] + tid * 8;
  u16* bsp = (u16*)&Bs[0][0] + tid * 8;

  auto stage = [&](int buf, int ko) {    // 8 loads/thread: 4 A-rows + 4 B-rows (rows sr + r*32)
    u16* ad = asp + buf * 8192;
    u16* bd = bsp + buf * 8192;
#pragma unroll
    for (int r = 0; r < 4; ++r)
      gload_lds16(agp + (size_t)r * 32 * HIDDEN + ko, ad + r * 2048);
#pragma unroll
    for (int r = 0; r < 4; ++r)
      gload_lds16(bgp + (size_t)r * 32 * HIDDEN + ko, bd + r * 2048);
  };

  const int sw = l15 & 7;
  const int c0 = (g ^ sw) * 8;
  const int c1 = ((g ^ sw) ^ 4) * 8;
  lptr aT = (lptr)&As[0][0] + (size_t)(wm * 64 + l15) * 64;
  lptr bT = (lptr)&Bs[0][0] + (size_t)(wn * 64 + l15) * 64;

  f32x4 acc[4][4] = {};
  bf16x8 Xa[4], Xb[4], Ya[4], Yb[4];

#define ISSUE8O(Sa, Sb, ab, bb) \
  DSR(Sa[0], ab, "0"); DSR(Sa[1], ab, "2048"); DSR(Sa[2], ab, "4096"); DSR(Sa[3], ab, "6144"); \
  DSR(Sb[0], bb, "0"); DSR(Sb[1], bb, "2048"); DSR(Sb[2], bb, "4096"); DSR(Sb[3], bb, "6144");

#define MFMA16O(Sa, Sb)                                                                   \
  _Pragma("unroll")                                                                       \
  for (int mf = 0; mf < 4; ++mf) {                                                        \
    _Pragma("unroll")                                                                     \
    for (int nf = 0; nf < 4; ++nf)                                                        \
      acc[mf][nf] = __builtin_amdgcn_mfma_f32_16x16x32_bf16(Sa[mf], Sb[nf], acc[mf][nf], 0, 0, 0); \
  }

  // ---- prologue
  stage(0, 0);
  stage(1, 64);
  asm volatile("s_waitcnt vmcnt(8)" ::: "memory");
  __builtin_amdgcn_s_barrier();
  __builtin_amdgcn_sched_barrier(0);
  {
    lptr ab = aT + c0;
    lptr bb = bT + c0;
    ISSUE8O(Xa, Xb, ab, bb)
  }

#pragma unroll 2
  for (int t = 0; t < 32; ++t) {
    const int cur = t & 1;
    {
      lptr ab = aT + cur * 8192 + c1;
      lptr bb = bT + cur * 8192 + c1;
      ISSUE8O(Ya, Yb, ab, bb)
    }
    asm volatile("s_waitcnt lgkmcnt(8)" ::: "memory");
    __builtin_amdgcn_sched_barrier(0);
    __builtin_amdgcn_s_setprio(1);
    MFMA16O(Xa, Xb)
    __builtin_amdgcn_s_setprio(0);
    asm volatile("s_waitcnt lgkmcnt(0)" ::: "memory");
    __builtin_amdgcn_sched_barrier(0);
    __builtin_amdgcn_s_barrier();
    __builtin_amdgcn_sched_barrier(0);
    if (t < 30) stage(cur, (t + 2) * 64);
    __builtin_amdgcn_sched_barrier(0);
    __builtin_amdgcn_s_setprio(1);
    MFMA16O(Ya, Yb)
    __builtin_amdgcn_s_setprio(0);
    __builtin_amdgcn_sched_barrier(0);
    if (t < 30) {
      asm volatile("s_waitcnt vmcnt(8)" ::: "memory");
    } else {
      asm volatile("s_waitcnt vmcnt(0)" ::: "memory");
    }
    __builtin_amdgcn_s_barrier();
    __builtin_amdgcn_sched_barrier(0);
    if (t < 31) {
      lptr ab = aT + (cur ^ 1) * 8192 + c0;
      lptr bb = bT + (cur ^ 1) * 8192 + c0;
      ISSUE8O(Xa, Xb, ab, bb)
    }
  }
#undef ISSUE8O
#undef MFMA16O

  // epilogue: f32 out + bias
#pragma unroll
  for (int mf = 0; mf < 4; ++mf) {
#pragma unroll
    for (int nf = 0; nf < 4; ++nf) {
      const int gc = tileN + wn * 64 + nf * 16 + l15;
      const float bv = bias[gc];
#pragma unroll
      for (int j = 0; j < 4; ++j) {
        const int gr = tileM + wm * 64 + mf * 16 + g * 4 + j;
        Cout[(size_t)gr * HIDDEN + gc] = acc[mf][nf][j] + bv;
      }
    }
  }
}

// ---------------- flash attention: KVBLK=64, 32 q/wave (2 groups), deferred l-reduction ----------------
__global__ __launch_bounds__(256, 2) void attn_kernel(
    const u16* __restrict__ QKg, const u16* __restrict__ Vtg, u16* __restrict__ Ctx)
{
  __shared__ __attribute__((aligned(16))) u16 Ks[2][64 * 128]; // 32 KiB
  __shared__ __attribute__((aligned(16))) u16 Vs[2][128 * 64]; // 32 KiB

  const int tid  = threadIdx.x;
  const int lane = tid & 63;
  const int wave = tid >> 6;
  const int g4   = lane >> 4;
  const int l15  = lane & 15;

  const int wg = ((blockIdx.x & 7) << 6) + (blockIdx.x >> 3);
  const int bh = wg >> 4;
  const int qt = wg & 15;
  const int b  = bh >> 4, h = bh & 15;

  const u16* Qb  = QKg + (size_t)b * SEQ * QSTR + (size_t)h * HD;
  const u16* Kb  = Qb + 2048;
  const u16* Vth = Vtg + (size_t)bh * HD * SEQ;
  u16* Cb = Ctx + (size_t)b * SEQ * HIDDEN + (size_t)h * HD;

  const int qbase = qt * 128 + wave * 32 + l15;   // q-group qs adds qs*16

  bf16x8 qf[2][4];
#pragma unroll
  for (int qs = 0; qs < 2; qs++)
#pragma unroll
    for (int dc = 0; dc < 4; dc++)
      qf[qs][dc] = ld_frag(Qb + (size_t)(qbase + qs * 16) * QSTR + dc * 32 + g4 * 8);

  const int kvp0 = (l15 >> 2) * 8 + (l15 & 3);
  const int msw  = (l15 & 3) | (((l15 >> 2) & 1) << 2);
  const int msw3 = msw & 3;
  const int mk   = (l15 >> 2) & 1;
  const int kcol = (g4 ^ msw3) * 8;

  lptr ksb = (lptr)&Ks[0][0];
  lptr kE0 = ksb + (kvp0      ) * 128 + kcol + mk * 32;
  lptr kO0 = ksb + (kvp0      ) * 128 + kcol + (1 ^ mk) * 32;
  lptr kE1 = ksb + (kvp0 +   4) * 128 + kcol + mk * 32;
  lptr kO1 = ksb + (kvp0 +   4) * 128 + kcol + (1 ^ mk) * 32;
  lptr kE2 = ksb + (kvp0 +  32) * 128 + kcol + mk * 32;
  lptr kO2 = ksb + (kvp0 +  32) * 128 + kcol + (1 ^ mk) * 32;
  lptr kE3 = ksb + (kvp0 +  36) * 128 + kcol + mk * 32;
  lptr kO3 = ksb + (kvp0 +  36) * 128 + kcol + (1 ^ mk) * 32;

  lptr vsb = (lptr)&Vs[0][0];
  lptr vB0 = vsb + l15 * 64 + ((0 * 4 + g4) ^ (l15 & 7)) * 8;
  lptr vB1 = vsb + l15 * 64 + ((1 * 4 + g4) ^ (l15 & 7)) * 8;

  const u16* kg[4];
  const u16* vg[4];
  u16* ksd = (u16*)&Ks[0][0] + tid * 8;
  u16* vsd = (u16*)&Vs[0][0] + tid * 8;
#pragma unroll
  for (int i = 0; i < 4; i++) {
    const int idx = tid + i * 256;
    const int kv = idx >> 4, up = idx & 15;
    const int um = up ^ ((kv & 3) | (((kv >> 3) & 1) << 2));
    kg[i] = Kb + (size_t)kv * QSTR + um * 8;
    const int d = idx >> 3, u = idx & 7;
    const int uv = u ^ (d & 7);
    vg[i] = Vth + (size_t)d * SEQ + uv * 8;
  }

  auto stage = [&](int buf, int kv0) {
    u16* kd = ksd + buf * 8192;
    u16* vd = vsd + buf * 8192;
#pragma unroll
    for (int i = 0; i < 4; i++) gload_lds16(kg[i] + (size_t)kv0 * QSTR, kd + i * 2048);
#pragma unroll
    for (int i = 0; i < 4; i++) gload_lds16(vg[i] + kv0, vd + i * 2048);
  };

  f32x4 ctx[2][8] = {};
  float m_run[2] = {-1e30f, -1e30f};
  float l_run[2] = {0.f, 0.f};           // per-lane PARTIAL (reduced once at epilogue)

  stage(0, 0);

  const int NT = SEQ / 64;
  for (int t = 0; t < NT; t++) {
    const int buf = t & 1;

    if (t + 1 < NT) {
      stage(buf ^ 1, (t + 1) * 64);
      asm volatile("s_waitcnt vmcnt(8)" ::: "memory");
    } else {
      asm volatile("s_waitcnt vmcnt(0)" ::: "memory");
    }
    __builtin_amdgcn_s_barrier();
    __builtin_amdgcn_sched_barrier(0);

    // [C] QK^T: 16 asm K-reads (shared by both q-groups), counted lgkm
    bf16x8 kf[4][4];
    {
      const int bo = buf * 8192;
      lptr e0 = kE0 + bo, o0 = kO0 + bo, e1 = kE1 + bo, o1 = kO1 + bo;
      lptr e2 = kE2 + bo, o2 = kO2 + bo, e3 = kE3 + bo, o3 = kO3 + bo;
      DSR(kf[0][0], e0, "0"); DSR(kf[0][1], o0, "0"); DSR(kf[0][2], e0, "128"); DSR(kf[0][3], o0, "128");
      DSR(kf[1][0], e1, "0"); DSR(kf[1][1], o1, "0"); DSR(kf[1][2], e1, "128"); DSR(kf[1][3], o1, "128");
      DSR(kf[2][0], e2, "0"); DSR(kf[2][1], o2, "0"); DSR(kf[2][2], e2, "128"); DSR(kf[2][3], o2, "128");
      DSR(kf[3][0], e3, "0"); DSR(kf[3][1], o3, "0"); DSR(kf[3][2], e3, "128"); DSR(kf[3][3], o3, "128");
    }
    f32x4 s[2][4] = {};
    asm volatile("s_waitcnt lgkmcnt(8)" ::: "memory");
    __builtin_amdgcn_sched_barrier(0);
    __builtin_amdgcn_s_setprio(1);
#pragma unroll
    for (int ni = 0; ni < 2; ni++)
#pragma unroll
      for (int dc = 0; dc < 4; dc++) {
        MFMA16(s[0][ni], kf[ni][dc], qf[0][dc]);
        MFMA16(s[1][ni], kf[ni][dc], qf[1][dc]);
      }
    __builtin_amdgcn_sched_barrier(0);
    asm volatile("s_waitcnt lgkmcnt(0)" ::: "memory");
    __builtin_amdgcn_sched_barrier(0);
#pragma unroll
    for (int ni = 2; ni < 4; ni++)
#pragma unroll
      for (int dc = 0; dc < 4; dc++) {
        MFMA16(s[0][ni], kf[ni][dc], qf[0][dc]);
        MFMA16(s[1][ni], kf[ni][dc], qf[1][dc]);
      }
    __builtin_amdgcn_s_setprio(0);
    __builtin_amdgcn_sched_barrier(0);

    // [D1] pmax trees + wave reduce (only ds-ops in softmax: the shuffles)
    float pmax[2];
#pragma unroll
    for (int qs = 0; qs < 2; qs++) {
      float m0 = fmaxf(fmaxf(s[qs][0][0], s[qs][0][1]), fmaxf(s[qs][0][2], s[qs][0][3]));
      float m1 = fmaxf(fmaxf(s[qs][1][0], s[qs][1][1]), fmaxf(s[qs][1][2], s[qs][1][3]));
      float m2 = fmaxf(fmaxf(s[qs][2][0], s[qs][2][1]), fmaxf(s[qs][2][2], s[qs][2][3]));
      float m3 = fmaxf(fmaxf(s[qs][3][0], s[qs][3][1]), fmaxf(s[qs][3][2], s[qs][3][3]));
      pmax[qs] = fmaxf(fmaxf(m0, m1), fmaxf(m2, m3));
      pmax[qs] = fmaxf(pmax[qs], __shfl_xor(pmax[qs], 16));
      pmax[qs] = fmaxf(pmax[qs], __shfl_xor(pmax[qs], 32));
    }
    __builtin_amdgcn_sched_barrier(0);   // shfl waits retire BEFORE asm V-reads

    // [D2] issue 16 V-reads early — latency hides under exp2/pack VALU below
    bf16x8 vf[2][8];
    {
      lptr v0 = vB0 + buf * 8192;
      lptr v1 = vB1 + buf * 8192;
      DSR(vf[0][0], v0, "0");     DSR(vf[0][1], v0, "2048");
      DSR(vf[0][2], v0, "4096");  DSR(vf[0][3], v0, "6144");
      DSR(vf[0][4], v0, "8192");  DSR(vf[0][5], v0, "10240");
      DSR(vf[0][6], v0, "12288"); DSR(vf[0][7], v0, "14336");
      DSR(vf[1][0], v1, "0");     DSR(vf[1][1], v1, "2048");
      DSR(vf[1][2], v1, "4096");  DSR(vf[1][3], v1, "6144");
      DSR(vf[1][4], v1, "8192");  DSR(vf[1][5], v1, "10240");
      DSR(vf[1][6], v1, "12288"); DSR(vf[1][7], v1, "14336");
    }
    __builtin_amdgcn_sched_barrier(0);

    // [D3] defer-max + exp2 + pack (no ds-ops -> V-read counts stay exact)
    const bool ok0 = (pmax[0] <= m_run[0] + 8.f);
    const bool ok1 = (pmax[1] <= m_run[1] + 8.f);
    if (!__all(ok0 && ok1)) {                     // defer-max (T13)
#pragma unroll
      for (int qs = 0; qs < 2; qs++) {
        const float mn = fmaxf(m_run[qs], pmax[qs]);
        const float corr = exp2f(m_run[qs] - mn);   // uniform across lanes sharing l15
        m_run[qs] = mn;
        l_run[qs] *= corr;
#pragma unroll
        for (int dt = 0; dt < 8; dt++)
#pragma unroll
          for (int j = 0; j < 4; j++) ctx[qs][dt][j] *= corr;
      }
    }
    bf16x8 pfrag[2][2];
#pragma unroll
    for (int qs = 0; qs < 2; qs++) {
      float ps = 0.f;
#pragma unroll
      for (int ni = 0; ni < 4; ni++)
#pragma unroll
        for (int j = 0; j < 4; j++) {
          const float p = exp2f(s[qs][ni][j] - m_run[qs]);
          s[qs][ni][j] = p;
          ps += p;
        }
      l_run[qs] += ps;                             // partial; reduced at epilogue
#pragma unroll
      for (int hh = 0; hh < 2; hh++) {
        u32x4 pw;
        pw[0] = pk2(s[qs][2 * hh][0], s[qs][2 * hh][1]);
        pw[1] = pk2(s[qs][2 * hh][2], s[qs][2 * hh][3]);
        pw[2] = pk2(s[qs][2 * hh + 1][0], s[qs][2 * hh + 1][1]);
        pw[3] = pk2(s[qs][2 * hh + 1][2], s[qs][2 * hh + 1][3]);
        pfrag[qs][hh] = __builtin_bit_cast(bf16x8, pw);
      }
    }
    __builtin_amdgcn_sched_barrier(0);

    // [E] PV: counted lgkm on the early-issued V-reads (FIFO: first 8 = vf[0][*])
    asm volatile("s_waitcnt lgkmcnt(8)" ::: "memory");
    __builtin_amdgcn_sched_barrier(0);
    __builtin_amdgcn_s_setprio(1);
#pragma unroll
    for (int dt = 0; dt < 8; dt++) {
      MFMA16(ctx[0][dt], vf[0][dt], pfrag[0][0]);
      MFMA16(ctx[1][dt], vf[0][dt], pfrag[1][0]);
    }
    __builtin_amdgcn_sched_barrier(0);
    asm volatile("s_waitcnt lgkmcnt(0)" ::: "memory");
    __builtin_amdgcn_sched_barrier(0);
#pragma unroll
    for (int dt = 0; dt < 8; dt++) {
      MFMA16(ctx[0][dt], vf[1][dt], pfrag[0][1]);
      MFMA16(ctx[1][dt], vf[1][dt], pfrag[1][1]);
    }
    __builtin_amdgcn_s_setprio(0);
    __builtin_amdgcn_sched_barrier(0);

    __builtin_amdgcn_s_barrier();
    __builtin_amdgcn_sched_barrier(0);
  }

  // epilogue: reduce l partial once, then d = dt*16 + g4*4 + j
#pragma unroll
  for (int qs = 0; qs < 2; qs++) {
    float lt = l_run[qs];
    lt += __shfl_xor(lt, 16);
    lt += __shfl_xor(lt, 32);
    const float linv = 1.f / lt;
    u16* crow = Cb + (size_t)(qbase + qs * 16) * HIDDEN;
#pragma unroll
    for (int dt = 0; dt < 8; dt++) {
      u16x4 o;
#pragma unroll
      for (int j = 0; j < 4; j++) o[j] = f2bf(ctx[qs][dt][j] * linv);
      *(u16x4*)&crow[dt * 16 + g4 * 4] = o;
    }
  }
}

// ---------------- launch ----------------
extern "C" void kernel_launch(void* const* d_in, const int* in_sizes, int n_in,
                              void* d_out, int out_size, void* d_ws, size_t ws_size,
                              hipStream_t stream) {
  (void)in_sizes; (void)n_in; (void)out_size; (void)ws_size;
  const float* x  = (const float*)d_in[0];
  const float* wq = (const float*)d_in[1];
  const float* bq = (const float*)d_in[2];
  const float* wk = (const float*)d_in[3];
  const float* bk = (const float*)d_in[4];
  const float* wv = (const float*)d_in[5];
  const float* bv = (const float*)d_in[6];
  const float* wo = (const float*)d_in[7];
  const float* bo = (const float*)d_in[8];

  const size_t NX = (size_t)BATCH * SEQ * HIDDEN;   // 8.39M
  const size_t NW = (size_t)HIDDEN * HIDDEN;        // 4.19M
  u16* xb   = (u16*)d_ws;            // [NX]
  u16* wqb  = xb  + NX;              // [3NW] contiguous Wq|Wk|Wv
  u16* wkb  = wqb + NW;
  u16* wvb  = wkb + NW;
  u16* wob  = wvb + NW;              // [NW]
  u16* qk   = wob + NW;              // [M,4096] fused Q|K
  u16* vtb  = qk  + 2 * NX;          // [B*H, D, S]
  u16* ctxb = xb;                    // x dead after projections

  // one fused conversion launch: 6 equal segments of NW/4 f32x4
  cvt6_kernel<<<dim3(512, 6), 256, 0, stream>>>(x, wq, wk, wv, wo,
                                                xb, wqb, wkb, wvb, wob, (int)(NW / 4));

  // 1/sqrt(128) * log2(e): scores in log2 units
  const float qscale = 0.12751744174240807f;
  gemm_qkv<<<512, 512, 0, stream>>>(xb, wqb, bq, bk, bv, qk, vtb, qscale);

  attn_kernel<<<512, 256, 0, stream>>>(qk, vtb, ctxb);

  gemm_o<<<512, 256, 0, stream>>>(ctxb, wob, bo, (float*)d_out);
}

// Round 12
// 244.774 us; speedup vs baseline: 1.0323x; 1.0323x over previous
//
#include <hip/hip_runtime.h>

typedef unsigned short u16;
typedef unsigned int   u32;
typedef float  f32x4   __attribute__((ext_vector_type(4)));
typedef __bf16 bf16x8  __attribute__((ext_vector_type(8)));
typedef u16    u16x8   __attribute__((ext_vector_type(8)));
typedef u16    u16x4   __attribute__((ext_vector_type(4)));
typedef u32    u32x2   __attribute__((ext_vector_type(2)));
typedef u32    u32x4   __attribute__((ext_vector_type(4)));

#define HIDDEN 2048
#define SEQ    2048
#define NHEADS 16
#define HD     128
#define BATCH  2
#define QSTR   4096   // fused Q|K row stride

typedef const __attribute__((address_space(3))) u16* lptr;

__device__ __forceinline__ u16 f2bf(float f) {
  u32 u = __builtin_bit_cast(u32, f);
  u += 0x7FFFu + ((u >> 16) & 1u);          // RNE
  return (u16)(u >> 16);
}
__device__ __forceinline__ u32 pk2(float a, float b) {
  __bf16 x = (__bf16)a, y = (__bf16)b;
  return (u32)__builtin_bit_cast(u16, x) | ((u32)__builtin_bit_cast(u16, y) << 16);
}
__device__ __forceinline__ bf16x8 ld_frag(const u16* p) {
  return __builtin_bit_cast(bf16x8, *(const u32x4*)p);
}
__device__ __forceinline__ void gload_lds16(const u16* g, u16* l) {
  __builtin_amdgcn_global_load_lds((const __attribute__((address_space(1))) u32*)g,
                                   (__attribute__((address_space(3))) u32*)l, 16, 0, 0);
}

// inline-asm LDS read: compiler inserts no auto-waits; we count lgkmcnt manually.
#define DSR(dst, base, lit) \
  asm volatile("ds_read_b128 %0, %1 offset:" lit : "=v"(dst) : "v"(base))

#define MFMA16(d, a, b) d = __builtin_amdgcn_mfma_f32_16x16x32_bf16(a, b, d, 0, 0, 0)

// ---------------- fp32 -> bf16 convert ----------------
__global__ __launch_bounds__(256) void cvt_kernel(const float* __restrict__ src,
                                                  u16* __restrict__ dst, int n4) {
  int stride = gridDim.x * blockDim.x;
  for (int i = blockIdx.x * blockDim.x + threadIdx.x; i < n4; i += stride) {
    f32x4 v = ((const f32x4*)src)[i];
    u16x4 o;
    o[0] = f2bf(v[0]); o[1] = f2bf(v[1]); o[2] = f2bf(v[2]); o[3] = f2bf(v[3]);
    *(u16x4*)(dst + (size_t)i * 4) = o;
  }
}

__global__ __launch_bounds__(256) void cvt4_kernel(
    const float* __restrict__ s0, const float* __restrict__ s1,
    const float* __restrict__ s2, const float* __restrict__ s3,
    u16* __restrict__ o0, u16* __restrict__ o1,
    u16* __restrict__ o2, u16* __restrict__ o3, int n4) {
  const float* src = (blockIdx.y == 0) ? s0 : (blockIdx.y == 1) ? s1 : (blockIdx.y == 2) ? s2 : s3;
  u16* dst = (blockIdx.y == 0) ? o0 : (blockIdx.y == 1) ? o1 : (blockIdx.y == 2) ? o2 : o3;
  int stride = gridDim.x * blockDim.x;
  for (int i = blockIdx.x * blockDim.x + threadIdx.x; i < n4; i += stride) {
    f32x4 v = ((const f32x4*)src)[i];
    u16x4 o;
    o[0] = f2bf(v[0]); o[1] = f2bf(v[1]); o[2] = f2bf(v[2]); o[3] = f2bf(v[3]);
    *(u16x4*)(dst + (size_t)i * 4) = o;
  }
}

// ---------------- fused QKV projection: 256Mx192N tile, BK=64, 8-wave, asm-counted pipeline ----------------
// PROVEN 118us config (round-7 bench): 2-phase counted waits, stage(t+2) issued before MFMA-Y.
__global__ __launch_bounds__(512, 2) void gemm_qkv(
    const u16* __restrict__ A, const u16* __restrict__ Bt,
    const float* __restrict__ bq, const float* __restrict__ bk,
    const float* __restrict__ bv,
    u16* __restrict__ qk, u16* __restrict__ vtb, float qscale)
{
  __shared__ __attribute__((aligned(16))) u16 As[2][16384];  // 64 KiB
  __shared__ __attribute__((aligned(16))) u16 Bs[2][12288];  // 48 KiB

  const int tid  = threadIdx.x;
  const int lane = tid & 63;
  const int wave = tid >> 6;
  const int l15  = lane & 15;
  const int g    = lane >> 4;
  const int wm   = wave >> 2;            // 0..1 (M half, 128 rows)
  const int wn   = wave & 3;             // 0..3 (N quarter, 48 cols)

  // grid 512 = 8 XCD * (4 Ntiles * 16 Mtiles); bijective
  const int id  = blockIdx.x;
  const int xcd = id & 7;
  const int c   = id >> 3;               // 0..63
  const int tileN = (xcd * 4 + (c >> 4)) * 192;
  const int tileM = (c & 15) << 8;

  // staging: thread covers row (tid>>3) of each 64-row round, chunk (tid&7)
  const int srow = tid >> 3;
  const int gch8 = ((tid & 7) ^ (srow & 7)) * 8;     // pre-swizzled global chunk
  const u16* agp = A  + (size_t)(tileM + srow) * HIDDEN + gch8;
  const u16* bgp = Bt + (size_t)(tileN + srow) * HIDDEN + gch8;
  u16* asp = (u16*)&As[0][0] + tid * 8;
  u16* bsp = (u16*)&Bs[0][0] + tid * 8;

  auto stage = [&](int buf, int ko) {
    u16* ad = asp + buf * 16384;
    u16* bd = bsp + buf * 12288;
#pragma unroll
    for (int r = 0; r < 4; ++r)
      gload_lds16(agp + (size_t)r * 64 * HIDDEN + ko, ad + r * 4096);
#pragma unroll
    for (int r = 0; r < 3; ++r)
      gload_lds16(bgp + (size_t)r * 64 * HIDDEN + ko, bd + r * 4096);
  };

  // fragment read bases (asm, byte offsets in literals): row stride 16 rows = 2048 B
  const int sw = l15 & 7;
  const int c0 = (g ^ sw) * 8;           // k0 chunk (elements)
  const int c1 = ((g ^ sw) ^ 4) * 8;     // k1 chunk
  lptr aT = (lptr)&As[0][0] + (size_t)(wm * 128 + l15) * 64;
  lptr bT = (lptr)&Bs[0][0] + (size_t)(wn * 48 + l15) * 64;

  f32x4 acc[8][3] = {};
  bf16x8 Xa[8], Xb[3], Ya[8], Yb[3];

#define ISSUE_SET(Sa, Sb, ab, bb)      \
  DSR(Sa[0], ab, "0");                 \
  DSR(Sa[1], ab, "2048");              \
  DSR(Sa[2], ab, "4096");              \
  DSR(Sa[3], ab, "6144");              \
  DSR(Sa[4], ab, "8192");              \
  DSR(Sa[5], ab, "10240");             \
  DSR(Sa[6], ab, "12288");             \
  DSR(Sa[7], ab, "14336");             \
  DSR(Sb[0], bb, "0");                 \
  DSR(Sb[1], bb, "2048");              \
  DSR(Sb[2], bb, "4096");

#define MFMA24(Sa, Sb)                                                                    \
  _Pragma("unroll")                                                                       \
  for (int mf = 0; mf < 8; ++mf) {                                                        \
    _Pragma("unroll")                                                                     \
    for (int nf = 0; nf < 3; ++nf)                                                        \
      acc[mf][nf] = __builtin_amdgcn_mfma_f32_16x16x32_bf16(Sa[mf], Sb[nf], acc[mf][nf], 0, 0, 0); \
  }

  // ---- prologue: stage tiles 0,1; wait tile0; issue X=(buf0,k0)
  stage(0, 0);
  stage(1, 64);
  asm volatile("s_waitcnt vmcnt(7)" ::: "memory");
  __builtin_amdgcn_s_barrier();
  __builtin_amdgcn_sched_barrier(0);
  {
    lptr ab = aT + c0;
    lptr bb = bT + c0;
    ISSUE_SET(Xa, Xb, ab, bb)
  }

#pragma unroll 2
  for (int t = 0; t < 32; ++t) {
    const int cur = t & 1;
    lptr aC = aT + cur * 16384;
    lptr bC = bT + cur * 12288;
    // [1] Y <- (cur, k1)
    {
      lptr ab = aC + c1;
      lptr bb = bC + c1;
      ISSUE_SET(Ya, Yb, ab, bb)
    }
    // [2] X ready (Y in flight)
    asm volatile("s_waitcnt lgkmcnt(11)" ::: "memory");
    __builtin_amdgcn_sched_barrier(0);
    __builtin_amdgcn_s_setprio(1);
    MFMA24(Xa, Xb)
    __builtin_amdgcn_s_setprio(0);
    // [3] Y ready; own reads of cur all retired
    asm volatile("s_waitcnt lgkmcnt(0)" ::: "memory");
    __builtin_amdgcn_sched_barrier(0);
    // [4] ALL waves' reads of cur retired -> cur may be overwritten
    __builtin_amdgcn_s_barrier();
    __builtin_amdgcn_sched_barrier(0);
    // [5] stage t+2 -> cur; issue+flight overlap MFMA Y
    if (t < 30) stage(cur, (t + 2) * 64);
    __builtin_amdgcn_sched_barrier(0);
    __builtin_amdgcn_s_setprio(1);
    MFMA24(Ya, Yb)
    __builtin_amdgcn_s_setprio(0);
    __builtin_amdgcn_sched_barrier(0);
    // [6] own t+1 landed (t+2 stays in flight)
    if (t < 30) {
      asm volatile("s_waitcnt vmcnt(7)" ::: "memory");
    } else {
      asm volatile("s_waitcnt vmcnt(0)" ::: "memory");
    }
    __builtin_amdgcn_s_barrier();
    __builtin_amdgcn_sched_barrier(0);
    // [7] X <- (nxt, k0)
    if (t < 31) {
      lptr ab = aT + (cur ^ 1) * 16384 + c0;
      lptr bb = bT + (cur ^ 1) * 12288 + c0;
      ISSUE_SET(Xa, Xb, ab, bb)
    }
  }

  // ---------- epilogue: Q|K -> qk (scaled, biased), V -> transposed vtb
#pragma unroll
  for (int mi = 0; mi < 8; ++mi) {
#pragma unroll
    for (int ni = 0; ni < 3; ++ni) {
      const int gcb = tileN + wn * 48 + ni * 16;
      const int seg = gcb >> 11;                     // 0=Q 1=K 2=V
      const int gc  = gcb + l15;
      const float bvv = ((seg == 0) ? bq : (seg == 1) ? bk : bv)[gc & 2047];
      if (seg < 2) {
        const float scl = (seg == 0) ? qscale : 1.f;
#pragma unroll
        for (int j = 0; j < 4; ++j) {
          const int gr = tileM + wm * 128 + mi * 16 + g * 4 + j;
          qk[(size_t)gr * QSTR + gc] = f2bf((acc[mi][ni][j] + bvv) * scl);
        }
      } else {
        const int dglob = gc - 4096;
        const int hh = dglob >> 7, dd = dglob & 127;
        const int srow0 = tileM + wm * 128 + mi * 16 + g * 4;
        const int bb = srow0 >> 11, ss = srow0 & 2047;
        u16x4 o;
#pragma unroll
        for (int j = 0; j < 4; ++j) o[j] = f2bf(acc[mi][ni][j] + bvv);
        *(u16x4*)(vtb + ((size_t)((bb * NHEADS + hh) * HD + dd)) * SEQ + ss) = o;
      }
    }
  }
#undef ISSUE_SET
#undef MFMA24
}

// ---------------- output projection: 256Mx128N tile, BK=64, 8-wave, asm-counted pipeline ----------------
__global__ __launch_bounds__(512, 2) void gemm_o(
    const u16* __restrict__ A, const u16* __restrict__ Bt,
    const float* __restrict__ bias, float* __restrict__ Cout)
{
  __shared__ __attribute__((aligned(16))) u16 As[2][16384];  // 256x64 x2 = 64 KiB
  __shared__ __attribute__((aligned(16))) u16 Bs[2][8192];   // 128x64 x2 = 32 KiB

  const int tid  = threadIdx.x;
  const int lane = tid & 63;
  const int wave = tid >> 6;
  const int l15  = lane & 15;
  const int g    = lane >> 4;
  const int wm   = wave >> 1;            // 0..3 (64-row band)
  const int wn   = wave & 1;             // 0..1 (64-col half)

  const int id  = blockIdx.x;
  const int xcd = id & 7;
  const int c   = id >> 3;               // 0..31
  const int tileN = (xcd * 2 + (c >> 4)) << 7;
  const int tileM = (c & 15) << 8;

  const int sr   = tid >> 3;
  const int sgc  = ((tid & 7) ^ (sr & 7)) * 8;       // pre-swizzled global chunk
  const u16* agp = A  + (size_t)(tileM + sr) * HIDDEN + sgc;
  const u16* bgp = Bt + (size_t)(tileN + sr) * HIDDEN + sgc;
  u16* asp = (u16*)&As[0][0] + tid * 8;
  u16* bsp = (u16*)&Bs[0][0] + tid * 8;

  auto stage = [&](int buf, int ko) {
    u16* ad = asp + buf * 16384;
    u16* bd = bsp + buf * 8192;
#pragma unroll
    for (int r = 0; r < 4; ++r)
      gload_lds16(agp + (size_t)r * 64 * HIDDEN + ko, ad + r * 4096);
#pragma unroll
    for (int r = 0; r < 2; ++r)
      gload_lds16(bgp + (size_t)r * 64 * HIDDEN + ko, bd + r * 4096);
  };

  const int sw = l15 & 7;
  const int c0 = (g ^ sw) * 8;
  const int c1 = ((g ^ sw) ^ 4) * 8;
  lptr aT = (lptr)&As[0][0] + (size_t)(wm * 64 + l15) * 64;
  lptr bT = (lptr)&Bs[0][0] + (size_t)(wn * 64 + l15) * 64;

  f32x4 acc[4][4] = {};
  bf16x8 Xa[4], Xb[4], Ya[4], Yb[4];

#define ISSUE8O(Sa, Sb, ab, bb) \
  DSR(Sa[0], ab, "0"); DSR(Sa[1], ab, "2048"); DSR(Sa[2], ab, "4096"); DSR(Sa[3], ab, "6144"); \
  DSR(Sb[0], bb, "0"); DSR(Sb[1], bb, "2048"); DSR(Sb[2], bb, "4096"); DSR(Sb[3], bb, "6144");

#define MFMA16O(Sa, Sb)                                                                   \
  _Pragma("unroll")                                                                       \
  for (int mf = 0; mf < 4; ++mf) {                                                        \
    _Pragma("unroll")                                                                     \
    for (int nf = 0; nf < 4; ++nf)                                                        \
      acc[mf][nf] = __builtin_amdgcn_mfma_f32_16x16x32_bf16(Sa[mf], Sb[nf], acc[mf][nf], 0, 0, 0); \
  }

  // ---- prologue
  stage(0, 0);
  stage(1, 64);
  asm volatile("s_waitcnt vmcnt(6)" ::: "memory");
  __builtin_amdgcn_s_barrier();
  __builtin_amdgcn_sched_barrier(0);
  {
    lptr ab = aT + c0;
    lptr bb = bT + c0;
    ISSUE8O(Xa, Xb, ab, bb)
  }

#pragma unroll 2
  for (int t = 0; t < 32; ++t) {
    const int cur = t & 1;
    {
      lptr ab = aT + cur * 16384 + c1;
      lptr bb = bT + cur * 8192 + c1;
      ISSUE8O(Ya, Yb, ab, bb)
    }
    asm volatile("s_waitcnt lgkmcnt(8)" ::: "memory");
    __builtin_amdgcn_sched_barrier(0);
    __builtin_amdgcn_s_setprio(1);
    MFMA16O(Xa, Xb)
    __builtin_amdgcn_s_setprio(0);
    asm volatile("s_waitcnt lgkmcnt(0)" ::: "memory");
    __builtin_amdgcn_sched_barrier(0);
    __builtin_amdgcn_s_barrier();
    __builtin_amdgcn_sched_barrier(0);
    if (t < 30) stage(cur, (t + 2) * 64);
    __builtin_amdgcn_sched_barrier(0);
    __builtin_amdgcn_s_setprio(1);
    MFMA16O(Ya, Yb)
    __builtin_amdgcn_s_setprio(0);
    __builtin_amdgcn_sched_barrier(0);
    if (t < 30) {
      asm volatile("s_waitcnt vmcnt(6)" ::: "memory");
    } else {
      asm volatile("s_waitcnt vmcnt(0)" ::: "memory");
    }
    __builtin_amdgcn_s_barrier();
    __builtin_amdgcn_sched_barrier(0);
    if (t < 31) {
      lptr ab = aT + (cur ^ 1) * 16384 + c0;
      lptr bb = bT + (cur ^ 1) * 8192 + c0;
      ISSUE8O(Xa, Xb, ab, bb)
    }
  }
#undef ISSUE8O
#undef MFMA16O

  // epilogue: f32 out + bias
#pragma unroll
  for (int mf = 0; mf < 4; ++mf) {
#pragma unroll
    for (int nf = 0; nf < 4; ++nf) {
      const int gc = tileN + wn * 64 + nf * 16 + l15;
      const float bv = bias[gc];
#pragma unroll
      for (int j = 0; j < 4; ++j) {
        const int gr = tileM + wm * 64 + mf * 16 + g * 4 + j;
        Cout[(size_t)gr * HIDDEN + gc] = acc[mf][nf][j] + bv;
      }
    }
  }
}

// ---------------- flash attention: KVBLK=64, 32 q/wave (2 groups), deferred l-reduction ----------------
// V-fragment ds_reads issued EARLY (after pmax shuffles, before exp2/pack) so their latency
// hides under the softmax VALU chain; sched_barrier(0) walls around (rule #18 class).
__global__ __launch_bounds__(256, 2) void attn_kernel(
    const u16* __restrict__ QKg, const u16* __restrict__ Vtg, u16* __restrict__ Ctx)
{
  __shared__ __attribute__((aligned(16))) u16 Ks[2][64 * 128]; // 32 KiB
  __shared__ __attribute__((aligned(16))) u16 Vs[2][128 * 64]; // 32 KiB

  const int tid  = threadIdx.x;
  const int lane = tid & 63;
  const int wave = tid >> 6;
  const int g4   = lane >> 4;
  const int l15  = lane & 15;

  const int wg = ((blockIdx.x & 7) << 6) + (blockIdx.x >> 3);
  const int bh = wg >> 4;
  const int qt = wg & 15;
  const int b  = bh >> 4, h = bh & 15;

  const u16* Qb  = QKg + (size_t)b * SEQ * QSTR + (size_t)h * HD;
  const u16* Kb  = Qb + 2048;
  const u16* Vth = Vtg + (size_t)bh * HD * SEQ;
  u16* Cb = Ctx + (size_t)b * SEQ * HIDDEN + (size_t)h * HD;

  const int qbase = qt * 128 + wave * 32 + l15;   // q-group qs adds qs*16

  bf16x8 qf[2][4];
#pragma unroll
  for (int qs = 0; qs < 2; qs++)
#pragma unroll
    for (int dc = 0; dc < 4; dc++)
      qf[qs][dc] = ld_frag(Qb + (size_t)(qbase + qs * 16) * QSTR + dc * 32 + g4 * 8);

  const int kvp0 = (l15 >> 2) * 8 + (l15 & 3);
  const int msw  = (l15 & 3) | (((l15 >> 2) & 1) << 2);
  const int msw3 = msw & 3;
  const int mk   = (l15 >> 2) & 1;
  const int kcol = (g4 ^ msw3) * 8;

  lptr ksb = (lptr)&Ks[0][0];
  lptr kE0 = ksb + (kvp0      ) * 128 + kcol + mk * 32;
  lptr kO0 = ksb + (kvp0      ) * 128 + kcol + (1 ^ mk) * 32;
  lptr kE1 = ksb + (kvp0 +   4) * 128 + kcol + mk * 32;
  lptr kO1 = ksb + (kvp0 +   4) * 128 + kcol + (1 ^ mk) * 32;
  lptr kE2 = ksb + (kvp0 +  32) * 128 + kcol + mk * 32;
  lptr kO2 = ksb + (kvp0 +  32) * 128 + kcol + (1 ^ mk) * 32;
  lptr kE3 = ksb + (kvp0 +  36) * 128 + kcol + mk * 32;
  lptr kO3 = ksb + (kvp0 +  36) * 128 + kcol + (1 ^ mk) * 32;

  lptr vsb = (lptr)&Vs[0][0];
  lptr vB0 = vsb + l15 * 64 + ((0 * 4 + g4) ^ (l15 & 7)) * 8;
  lptr vB1 = vsb + l15 * 64 + ((1 * 4 + g4) ^ (l15 & 7)) * 8;

  const u16* kg[4];
  const u16* vg[4];
  u16* ksd = (u16*)&Ks[0][0] + tid * 8;
  u16* vsd = (u16*)&Vs[0][0] + tid * 8;
#pragma unroll
  for (int i = 0; i < 4; i++) {
    const int idx = tid + i * 256;
    const int kv = idx >> 4, up = idx & 15;
    const int um = up ^ ((kv & 3) | (((kv >> 3) & 1) << 2));
    kg[i] = Kb + (size_t)kv * QSTR + um * 8;
    const int d = idx >> 3, u = idx & 7;
    const int uv = u ^ (d & 7);
    vg[i] = Vth + (size_t)d * SEQ + uv * 8;
  }

  auto stage = [&](int buf, int kv0) {
    u16* kd = ksd + buf * 8192;
    u16* vd = vsd + buf * 8192;
#pragma unroll
    for (int i = 0; i < 4; i++) gload_lds16(kg[i] + (size_t)kv0 * QSTR, kd + i * 2048);
#pragma unroll
    for (int i = 0; i < 4; i++) gload_lds16(vg[i] + kv0, vd + i * 2048);
  };

  f32x4 ctx[2][8] = {};
  float m_run[2] = {-1e30f, -1e30f};
  float l_run[2] = {0.f, 0.f};           // per-lane PARTIAL (reduced once at epilogue)

  stage(0, 0);

  const int NT = SEQ / 64;
  for (int t = 0; t < NT; t++) {
    const int buf = t & 1;

    if (t + 1 < NT) {
      stage(buf ^ 1, (t + 1) * 64);
      asm volatile("s_waitcnt vmcnt(8)" ::: "memory");
    } else {
      asm volatile("s_waitcnt vmcnt(0)" ::: "memory");
    }
    __builtin_amdgcn_s_barrier();
    __builtin_amdgcn_sched_barrier(0);

    // [C] QK^T: 16 asm K-reads (shared by both q-groups), counted lgkm
    bf16x8 kf[4][4];
    {
      const int bo = buf * 8192;
      lptr e0 = kE0 + bo, o0 = kO0 + bo, e1 = kE1 + bo, o1 = kO1 + bo;
      lptr e2 = kE2 + bo, o2 = kO2 + bo, e3 = kE3 + bo, o3 = kO3 + bo;
      DSR(kf[0][0], e0, "0"); DSR(kf[0][1], o0, "0"); DSR(kf[0][2], e0, "128"); DSR(kf[0][3], o0, "128");
      DSR(kf[1][0], e1, "0"); DSR(kf[1][1], o1, "0"); DSR(kf[1][2], e1, "128"); DSR(kf[1][3], o1, "128");
      DSR(kf[2][0], e2, "0"); DSR(kf[2][1], o2, "0"); DSR(kf[2][2], e2, "128"); DSR(kf[2][3], o2, "128");
      DSR(kf[3][0], e3, "0"); DSR(kf[3][1], o3, "0"); DSR(kf[3][2], e3, "128"); DSR(kf[3][3], o3, "128");
    }
    f32x4 s[2][4] = {};
    asm volatile("s_waitcnt lgkmcnt(8)" ::: "memory");
    __builtin_amdgcn_sched_barrier(0);
    __builtin_amdgcn_s_setprio(1);
#pragma unroll
    for (int ni = 0; ni < 2; ni++)
#pragma unroll
      for (int dc = 0; dc < 4; dc++) {
        MFMA16(s[0][ni], kf[ni][dc], qf[0][dc]);
        MFMA16(s[1][ni], kf[ni][dc], qf[1][dc]);
      }
    __builtin_amdgcn_sched_barrier(0);
    asm volatile("s_waitcnt lgkmcnt(0)" ::: "memory");
    __builtin_amdgcn_sched_barrier(0);
#pragma unroll
    for (int ni = 2; ni < 4; ni++)
#pragma unroll
      for (int dc = 0; dc < 4; dc++) {
        MFMA16(s[0][ni], kf[ni][dc], qf[0][dc]);
        MFMA16(s[1][ni], kf[ni][dc], qf[1][dc]);
      }
    __builtin_amdgcn_s_setprio(0);
    __builtin_amdgcn_sched_barrier(0);

    // [D1] pmax trees + wave reduce (only ds-ops in softmax: the shuffles)
    float pmax[2];
#pragma unroll
    for (int qs = 0; qs < 2; qs++) {
      float m0 = fmaxf(fmaxf(s[qs][0][0], s[qs][0][1]), fmaxf(s[qs][0][2], s[qs][0][3]));
      float m1 = fmaxf(fmaxf(s[qs][1][0], s[qs][1][1]), fmaxf(s[qs][1][2], s[qs][1][3]));
      float m2 = fmaxf(fmaxf(s[qs][2][0], s[qs][2][1]), fmaxf(s[qs][2][2], s[qs][2][3]));
      float m3 = fmaxf(fmaxf(s[qs][3][0], s[qs][3][1]), fmaxf(s[qs][3][2], s[qs][3][3]));
      pmax[qs] = fmaxf(fmaxf(m0, m1), fmaxf(m2, m3));
      pmax[qs] = fmaxf(pmax[qs], __shfl_xor(pmax[qs], 16));
      pmax[qs] = fmaxf(pmax[qs], __shfl_xor(pmax[qs], 32));
    }
    __builtin_amdgcn_sched_barrier(0);   // shfl waits retire BEFORE asm V-reads

    // [D2] issue 16 V-reads early — latency hides under exp2/pack VALU below
    bf16x8 vf[2][8];
    {
      lptr v0 = vB0 + buf * 8192;
      lptr v1 = vB1 + buf * 8192;
      DSR(vf[0][0], v0, "0");     DSR(vf[0][1], v0, "2048");
      DSR(vf[0][2], v0, "4096");  DSR(vf[0][3], v0, "6144");
      DSR(vf[0][4], v0, "8192");  DSR(vf[0][5], v0, "10240");
      DSR(vf[0][6], v0, "12288"); DSR(vf[0][7], v0, "14336");
      DSR(vf[1][0], v1, "0");     DSR(vf[1][1], v1, "2048");
      DSR(vf[1][2], v1, "4096");  DSR(vf[1][3], v1, "6144");
      DSR(vf[1][4], v1, "8192");  DSR(vf[1][5], v1, "10240");
      DSR(vf[1][6], v1, "12288"); DSR(vf[1][7], v1, "14336");
    }
    __builtin_amdgcn_sched_barrier(0);

    // [D3] defer-max + exp2 + pack (no ds-ops -> V-read counts stay exact)
    const bool ok0 = (pmax[0] <= m_run[0] + 8.f);
    const bool ok1 = (pmax[1] <= m_run[1] + 8.f);
    if (!__all(ok0 && ok1)) {                     // defer-max (T13)
#pragma unroll
      for (int qs = 0; qs < 2; qs++) {
        const float mn = fmaxf(m_run[qs], pmax[qs]);
        const float corr = exp2f(m_run[qs] - mn);   // uniform across lanes sharing l15
        m_run[qs] = mn;
        l_run[qs] *= corr;
#pragma unroll
        for (int dt = 0; dt < 8; dt++)
#pragma unroll
          for (int j = 0; j < 4; j++) ctx[qs][dt][j] *= corr;
      }
    }
    bf16x8 pfrag[2][2];
#pragma unroll
    for (int qs = 0; qs < 2; qs++) {
      float ps = 0.f;
#pragma unroll
      for (int ni = 0; ni < 4; ni++)
#pragma unroll
        for (int j = 0; j < 4; j++) {
          const float p = exp2f(s[qs][ni][j] - m_run[qs]);
          s[qs][ni][j] = p;
          ps += p;
        }
      l_run[qs] += ps;                             // partial; reduced at epilogue
#pragma unroll
      for (int hh = 0; hh < 2; hh++) {
        u32x4 pw;
        pw[0] = pk2(s[qs][2 * hh][0], s[qs][2 * hh][1]);
        pw[1] = pk2(s[qs][2 * hh][2], s[qs][2 * hh][3]);
        pw[2] = pk2(s[qs][2 * hh + 1][0], s[qs][2 * hh + 1][1]);
        pw[3] = pk2(s[qs][2 * hh + 1][2], s[qs][2 * hh + 1][3]);
        pfrag[qs][hh] = __builtin_bit_cast(bf16x8, pw);
      }
    }
    __builtin_amdgcn_sched_barrier(0);

    // [E] PV: counted lgkm on the early-issued V-reads (FIFO: first 8 = vf[0][*])
    asm volatile("s_waitcnt lgkmcnt(8)" ::: "memory");
    __builtin_amdgcn_sched_barrier(0);
    __builtin_amdgcn_s_setprio(1);
#pragma unroll
    for (int dt = 0; dt < 8; dt++) {
      MFMA16(ctx[0][dt], vf[0][dt], pfrag[0][0]);
      MFMA16(ctx[1][dt], vf[0][dt], pfrag[1][0]);
    }
    __builtin_amdgcn_sched_barrier(0);
    asm volatile("s_waitcnt lgkmcnt(0)" ::: "memory");
    __builtin_amdgcn_sched_barrier(0);
#pragma unroll
    for (int dt = 0; dt < 8; dt++) {
      MFMA16(ctx[0][dt], vf[1][dt], pfrag[0][1]);
      MFMA16(ctx[1][dt], vf[1][dt], pfrag[1][1]);
    }
    __builtin_amdgcn_s_setprio(0);
    __builtin_amdgcn_sched_barrier(0);

    __builtin_amdgcn_s_barrier();
    __builtin_amdgcn_sched_barrier(0);
  }

  // epilogue: reduce l partial once, then d = dt*16 + g4*4 + j
#pragma unroll
  for (int qs = 0; qs < 2; qs++) {
    float lt = l_run[qs];
    lt += __shfl_xor(lt, 16);
    lt += __shfl_xor(lt, 32);
    const float linv = 1.f / lt;
    u16* crow = Cb + (size_t)(qbase + qs * 16) * HIDDEN;
#pragma unroll
    for (int dt = 0; dt < 8; dt++) {
      u16x4 o;
#pragma unroll
      for (int j = 0; j < 4; j++) o[j] = f2bf(ctx[qs][dt][j] * linv);
      *(u16x4*)&crow[dt * 16 + g4 * 4] = o;
    }
  }
}

// ---------------- launch ----------------
extern "C" void kernel_launch(void* const* d_in, const int* in_sizes, int n_in,
                              void* d_out, int out_size, void* d_ws, size_t ws_size,
                              hipStream_t stream) {
  (void)in_sizes; (void)n_in; (void)out_size; (void)ws_size;
  const float* x  = (const float*)d_in[0];
  const float* wq = (const float*)d_in[1];
  const float* bq = (const float*)d_in[2];
  const float* wk = (const float*)d_in[3];
  const float* bk = (const float*)d_in[4];
  const float* wv = (const float*)d_in[5];
  const float* bv = (const float*)d_in[6];
  const float* wo = (const float*)d_in[7];
  const float* bo = (const float*)d_in[8];

  const size_t NX = (size_t)BATCH * SEQ * HIDDEN;   // 8.39M
  const size_t NW = (size_t)HIDDEN * HIDDEN;        // 4.19M
  u16* xb   = (u16*)d_ws;            // [NX]
  u16* wqb  = xb  + NX;              // [3NW] contiguous Wq|Wk|Wv
  u16* wkb  = wqb + NW;
  u16* wvb  = wkb + NW;
  u16* wob  = wvb + NW;              // [NW]
  u16* qk   = wob + NW;              // [M,4096] fused Q|K
  u16* vtb  = qk  + 2 * NX;          // [B*H, D, S]
  u16* ctxb = xb;                    // x dead after projections

  cvt_kernel<<<2048, 256, 0, stream>>>(x, xb, (int)(NX / 4));
  cvt4_kernel<<<dim3(512, 4), 256, 0, stream>>>(wq, wk, wv, wo, wqb, wkb, wvb, wob, (int)(NW / 4));

  // 1/sqrt(128) * log2(e): scores in log2 units
  const float qscale = 0.12751744174240807f;
  gemm_qkv<<<512, 512, 0, stream>>>(xb, wqb, bq, bk, bv, qk, vtb, qscale);

  attn_kernel<<<512, 256, 0, stream>>>(qk, vtb, ctxb);

  gemm_o<<<256, 512, 0, stream>>>(ctxb, wob, bo, (float*)d_out);
}